// Round 1
// baseline (475.668 us; speedup 1.0000x reference)
//
#include <hip/hip_runtime.h>

// Geometry (hard-coded from reference): B=8, N=1280 (256 t + 1024 s), C=768, H=12, hd=64
// Pipeline: cvt(fp32->bf16) -> gemm_qkv (scatter q,k,vT bf16) -> flash attention -> gemm_proj(+bias) -> fp32 out

typedef __attribute__((ext_vector_type(8))) short s8v;           // 8 x bf16 (MFMA A/B frag)
typedef __attribute__((ext_vector_type(4))) short s4v;
typedef __attribute__((ext_vector_type(4))) float f4v;           // MFMA C/D frag
typedef __attribute__((ext_vector_type(4))) unsigned short u4v;

#define MFMA16(a, b, c) __builtin_amdgcn_mfma_f32_16x16x32_bf16((a), (b), (c), 0, 0, 0)

__device__ __forceinline__ unsigned short f2bf(float f) {
  unsigned int u = __builtin_bit_cast(unsigned int, f);
  u += 0x7fffu + ((u >> 16) & 1u);      // round-to-nearest-even
  return (unsigned short)(u >> 16);
}

__global__ __launch_bounds__(256) void cvt_kernel(const float* __restrict__ src,
                                                  unsigned short* __restrict__ dst,
                                                  int n4) {
  int i = blockIdx.x * 256 + threadIdx.x;
  if (i < n4) {
    f4v v = ((const f4v*)src)[i];
    u4v o;
    o[0] = f2bf(v[0]); o[1] = f2bf(v[1]); o[2] = f2bf(v[2]); o[3] = f2bf(v[3]);
    ((u4v*)dst)[i] = o;
  }
}

// ---------------- 128x128 bf16 GEMM (C = A * B^T), K=768, both operands row-major [rows][K] ----
// block = 256 threads (4 waves, 2x2), wave tile 64x64 = 4x4 C-frags of 16x16.
// QKV variant: epilogue scatters to q[b,h,n,d], k[b,h,n,d], vT[b,h,d,n] (bf16).

__global__ __launch_bounds__(256) void gemm_qkv_kernel(
    const unsigned short* __restrict__ A,   // 10240 x 768 bf16 (x)
    const unsigned short* __restrict__ Bm,  // 2304 x 768 bf16 (qkv_w)
    unsigned short* __restrict__ qb, unsigned short* __restrict__ kb,
    unsigned short* __restrict__ vT) {
  const int K = 768;
  __shared__ __align__(16) unsigned short As[128 * 32];
  __shared__ __align__(16) unsigned short Bs[128 * 32];
  int tid = threadIdx.x;
  int wave = tid >> 6, lane = tid & 63;
  int quad = lane >> 4, l16 = lane & 15;
  int wm = wave >> 1, wn = wave & 1;
  int m0 = blockIdx.y * 128, n0 = blockIdx.x * 128;

  f4v acc[4][4];
#pragma unroll
  for (int i = 0; i < 4; ++i)
#pragma unroll
    for (int j = 0; j < 4; ++j) acc[i][j] = (f4v){0.f, 0.f, 0.f, 0.f};

  for (int kt = 0; kt < K; kt += 32) {
#pragma unroll
    for (int c = 0; c < 2; ++c) {
      int idx = c * 256 + tid;        // 16B-chunk id, 0..511 ; LDS off = idx*16 = wave base + lane*16
      int row = idx >> 2;
      int col = (idx & 3) << 3;
      const unsigned short* ga = A + (size_t)(m0 + row) * K + (kt + col);
      const unsigned short* gb = Bm + (size_t)(n0 + row) * K + (kt + col);
      __builtin_amdgcn_global_load_lds(
          (const __attribute__((address_space(1))) unsigned int*)ga,
          (__attribute__((address_space(3))) unsigned int*)((char*)As + idx * 16), 16, 0, 0);
      __builtin_amdgcn_global_load_lds(
          (const __attribute__((address_space(1))) unsigned int*)gb,
          (__attribute__((address_space(3))) unsigned int*)((char*)Bs + idx * 16), 16, 0, 0);
    }
    __syncthreads();                   // drains vmcnt -> LDS tiles ready
    s8v af[4], bfr[4];
#pragma unroll
    for (int mi = 0; mi < 4; ++mi)
      af[mi] = *(const s8v*)&As[(wm * 64 + mi * 16 + l16) * 32 + quad * 8];
#pragma unroll
    for (int ni = 0; ni < 4; ++ni)
      bfr[ni] = *(const s8v*)&Bs[(wn * 64 + ni * 16 + l16) * 32 + quad * 8];
#pragma unroll
    for (int mi = 0; mi < 4; ++mi)
#pragma unroll
      for (int ni = 0; ni < 4; ++ni)
        acc[mi][ni] = MFMA16(af[mi], bfr[ni], acc[mi][ni]);
    __syncthreads();                   // all waves done reading before next stage
  }

  // Epilogue scatter. C/D layout: row = quad*4+reg, col = l16 (verified m89/m91).
#pragma unroll
  for (int ni = 0; ni < 4; ++ni) {
    int gn = n0 + wn * 64 + ni * 16 + l16;   // output channel o in [0,2304)
    int which = gn / 768;                    // 0=q 1=k 2=v (uniform per frag)
    int oo = gn - which * 768;
    int hh = oo >> 6;
    int dd = oo & 63;
#pragma unroll
    for (int mi = 0; mi < 4; ++mi) {
#pragma unroll
      for (int r = 0; r < 4; ++r) {
        int gm = m0 + wm * 64 + mi * 16 + quad * 4 + r;  // token row in [0,10240)
        int bb = gm / 1280;
        int nn = gm - bb * 1280;
        unsigned short o = f2bf(acc[mi][ni][r]);
        if (which == 0)
          qb[(((size_t)bb * 12 + hh) * 1280 + nn) * 64 + dd] = o;
        else if (which == 1)
          kb[(((size_t)bb * 12 + hh) * 1280 + nn) * 64 + dd] = o;
        else
          vT[(((size_t)bb * 12 + hh) * 64 + dd) * 1280 + nn] = o;  // V transposed for PV B-frags
      }
    }
  }
}

__global__ __launch_bounds__(256) void gemm_proj_kernel(
    const unsigned short* __restrict__ A,   // 10240 x 768 bf16 (attention out)
    const unsigned short* __restrict__ Bm,  // 768 x 768 bf16 (proj_w)
    const float* __restrict__ pb, float* __restrict__ out) {
  const int K = 768;
  __shared__ __align__(16) unsigned short As[128 * 32];
  __shared__ __align__(16) unsigned short Bs[128 * 32];
  int tid = threadIdx.x;
  int wave = tid >> 6, lane = tid & 63;
  int quad = lane >> 4, l16 = lane & 15;
  int wm = wave >> 1, wn = wave & 1;
  int m0 = blockIdx.y * 128, n0 = blockIdx.x * 128;

  f4v acc[4][4];
#pragma unroll
  for (int i = 0; i < 4; ++i)
#pragma unroll
    for (int j = 0; j < 4; ++j) acc[i][j] = (f4v){0.f, 0.f, 0.f, 0.f};

  for (int kt = 0; kt < K; kt += 32) {
#pragma unroll
    for (int c = 0; c < 2; ++c) {
      int idx = c * 256 + tid;
      int row = idx >> 2;
      int col = (idx & 3) << 3;
      const unsigned short* ga = A + (size_t)(m0 + row) * K + (kt + col);
      const unsigned short* gb = Bm + (size_t)(n0 + row) * K + (kt + col);
      __builtin_amdgcn_global_load_lds(
          (const __attribute__((address_space(1))) unsigned int*)ga,
          (__attribute__((address_space(3))) unsigned int*)((char*)As + idx * 16), 16, 0, 0);
      __builtin_amdgcn_global_load_lds(
          (const __attribute__((address_space(1))) unsigned int*)gb,
          (__attribute__((address_space(3))) unsigned int*)((char*)Bs + idx * 16), 16, 0, 0);
    }
    __syncthreads();
    s8v af[4], bfr[4];
#pragma unroll
    for (int mi = 0; mi < 4; ++mi)
      af[mi] = *(const s8v*)&As[(wm * 64 + mi * 16 + l16) * 32 + quad * 8];
#pragma unroll
    for (int ni = 0; ni < 4; ++ni)
      bfr[ni] = *(const s8v*)&Bs[(wn * 64 + ni * 16 + l16) * 32 + quad * 8];
#pragma unroll
    for (int mi = 0; mi < 4; ++mi)
#pragma unroll
      for (int ni = 0; ni < 4; ++ni)
        acc[mi][ni] = MFMA16(af[mi], bfr[ni], acc[mi][ni]);
    __syncthreads();
  }

#pragma unroll
  for (int ni = 0; ni < 4; ++ni) {
    int gn = n0 + wn * 64 + ni * 16 + l16;
    float bias = pb[gn];
#pragma unroll
    for (int mi = 0; mi < 4; ++mi)
#pragma unroll
      for (int r = 0; r < 4; ++r) {
        int gm = m0 + wm * 64 + mi * 16 + quad * 4 + r;
        out[(size_t)gm * 768 + gn] = acc[mi][ni][r] + bias;
      }
  }
}

// ---------------- Flash attention ----------------
// grid (20, 12, 8): qtile 0..3 -> t-branch (keys 0..255), 4..19 -> s-branch (keys 0..1279).
// block 256 = 4 waves; wave handles 16 queries x hd=64, 32-key tiles, online softmax.
__global__ __launch_bounds__(256) void attn_kernel(
    const unsigned short* __restrict__ qb, const unsigned short* __restrict__ kb,
    const unsigned short* __restrict__ vT, unsigned short* __restrict__ attnb) {
  const int NT = 1280, CC = 768;
  int qt = blockIdx.x;
  int h = blockIdx.y;
  int b = blockIdx.z;
  int wave = threadIdx.x >> 6, lane = threadIdx.x & 63;
  int quad = lane >> 4, l16 = lane & 15;
  int q0 = qt * 64 + wave * 16;
  int nk = (qt < 4) ? 256 : 1280;

  const unsigned short* qp = qb + (((size_t)b * 12 + h) * NT + q0) * 64;
  const unsigned short* kp = kb + (((size_t)b * 12 + h) * NT) * 64;
  const unsigned short* vp = vT + (((size_t)b * 12 + h) * 64) * NT;

  // Q A-frags: A[m=l16][k=quad*8+j], k in 0..31 / 32..63
  s8v aq0 = *(const s8v*)(qp + l16 * 64 + quad * 8);
  s8v aq1 = *(const s8v*)(qp + l16 * 64 + 32 + quad * 8);

  // per-wave P tile for C-layout -> A-layout round trip; stride 40 (bank-friendly, 8B aligned)
  __shared__ __align__(16) unsigned short plds[4][16][40];
  unsigned short(*pw)[40] = plds[wave];

  float m_run[4], l_run[4];
  f4v Oacc[4];
#pragma unroll
  for (int r = 0; r < 4; ++r) { m_run[r] = -1e30f; l_run[r] = 0.f; }
#pragma unroll
  for (int dt = 0; dt < 4; ++dt) Oacc[dt] = (f4v){0.f, 0.f, 0.f, 0.f};

  const float scale = 0.125f;  // hd^-0.5

  for (int k0 = 0; k0 < nk; k0 += 32) {
    f4v s0 = {0.f, 0.f, 0.f, 0.f}, s1 = {0.f, 0.f, 0.f, 0.f};
    const unsigned short* kr0 = kp + (size_t)(k0 + l16) * 64;
    const unsigned short* kr1 = kp + (size_t)(k0 + 16 + l16) * 64;
    s0 = MFMA16(aq0, *(const s8v*)(kr0 + quad * 8), s0);
    s0 = MFMA16(aq1, *(const s8v*)(kr0 + 32 + quad * 8), s0);
    s1 = MFMA16(aq0, *(const s8v*)(kr1 + quad * 8), s1);
    s1 = MFMA16(aq1, *(const s8v*)(kr1 + 32 + quad * 8), s1);

    // lane holds rows quad*4+r (cols l16 / 16+l16); row stats reduce over the 16 lanes of the quad
    float sv0[4], sv1[4], pm[4];
#pragma unroll
    for (int r = 0; r < 4; ++r) {
      sv0[r] = s0[r] * scale;
      sv1[r] = s1[r] * scale;
      pm[r] = fmaxf(sv0[r], sv1[r]);
    }
#pragma unroll
    for (int off = 1; off < 16; off <<= 1)
#pragma unroll
      for (int r = 0; r < 4; ++r) pm[r] = fmaxf(pm[r], __shfl_xor(pm[r], off, 64));

    float al[4], p0[4], p1[4], rs[4];
#pragma unroll
    for (int r = 0; r < 4; ++r) {
      float nm = fmaxf(m_run[r], pm[r]);
      al[r] = __expf(m_run[r] - nm);
      m_run[r] = nm;
      p0[r] = __expf(sv0[r] - nm);
      p1[r] = __expf(sv1[r] - nm);
      rs[r] = p0[r] + p1[r];
    }
#pragma unroll
    for (int off = 1; off < 16; off <<= 1)
#pragma unroll
      for (int r = 0; r < 4; ++r) rs[r] += __shfl_xor(rs[r], off, 64);
#pragma unroll
    for (int r = 0; r < 4; ++r) l_run[r] = l_run[r] * al[r] + rs[r];
#pragma unroll
    for (int dt = 0; dt < 4; ++dt)
#pragma unroll
      for (int r = 0; r < 4; ++r) Oacc[dt][r] *= al[r];

    // P: C-layout -> LDS -> A-layout (wave-private region; per-wave DS pipe is in-order)
#pragma unroll
    for (int r = 0; r < 4; ++r) {
      pw[quad * 4 + r][l16] = f2bf(p0[r]);
      pw[quad * 4 + r][16 + l16] = f2bf(p1[r]);
    }
    __asm__ __volatile__("s_waitcnt lgkmcnt(0)" ::: "memory");
    s4v palo = *(const s4v*)&pw[l16][quad * 8];
    s4v pahi = *(const s4v*)&pw[l16][quad * 8 + 4];
    s8v pa = __builtin_shufflevector(palo, pahi, 0, 1, 2, 3, 4, 5, 6, 7);

    // PV: B[k=k0+quad*8+j][n=dt*16+l16] = vT[dt*16+l16][k0+quad*8+j] -> contiguous 16B
#pragma unroll
    for (int dt = 0; dt < 4; ++dt) {
      s8v bv = *(const s8v*)(vp + (size_t)(dt * 16 + l16) * NT + k0 + quad * 8);
      Oacc[dt] = MFMA16(pa, bv, Oacc[dt]);
    }
  }

  float inv[4];
#pragma unroll
  for (int r = 0; r < 4; ++r) inv[r] = 1.f / l_run[r];
#pragma unroll
  for (int dt = 0; dt < 4; ++dt)
#pragma unroll
    for (int r = 0; r < 4; ++r) {
      int n = q0 + quad * 4 + r;
      attnb[((size_t)b * NT + n) * CC + h * 64 + dt * 16 + l16] = f2bf(Oacc[dt][r] * inv[r]);
    }
}

extern "C" void kernel_launch(void* const* d_in, const int* in_sizes, int n_in,
                              void* d_out, int out_size, void* d_ws, size_t ws_size,
                              hipStream_t stream) {
  const float* x = (const float*)d_in[0];       // (8,1280,768)
  const float* qkv_w = (const float*)d_in[1];   // (2304,768)
  const float* proj_w = (const float*)d_in[2];  // (768,768)
  const float* proj_b = (const float*)d_in[3];  // (768,)
  float* out = (float*)d_out;

  // workspace layout (bytes)
  char* ws = (char*)d_ws;
  unsigned short* xb = (unsigned short*)(ws + 0);            // 10240*768*2 = 15,728,640
  unsigned short* wqkvb = (unsigned short*)(ws + 15728640);  // 2304*768*2  =  3,538,944
  unsigned short* wpb = (unsigned short*)(ws + 19267584);    // 768*768*2   =  1,179,648
  unsigned short* qb = (unsigned short*)(ws + 20447232);     // 15,728,640
  unsigned short* kbuf = (unsigned short*)(ws + 36175872);   // 15,728,640
  unsigned short* vT = (unsigned short*)(ws + 51904512);     // 15,728,640  -> total 67,633,152
  unsigned short* attnb = xb;  // reuse: xb dead after gemm_qkv

  cvt_kernel<<<dim3(1966080 / 256), 256, 0, stream>>>(x, xb, 1966080);
  cvt_kernel<<<dim3(442368 / 256), 256, 0, stream>>>(qkv_w, wqkvb, 442368);
  cvt_kernel<<<dim3(576), 256, 0, stream>>>(proj_w, wpb, 147456);

  gemm_qkv_kernel<<<dim3(18, 80), 256, 0, stream>>>(xb, wqkvb, qb, kbuf, vT);
  attn_kernel<<<dim3(20, 12, 8), 256, 0, stream>>>(qb, kbuf, vT, attnb);
  gemm_proj_kernel<<<dim3(6, 80), 256, 0, stream>>>(attnb, wpb, proj_b, out);
}

// Round 2
// 468.184 us; speedup vs baseline: 1.0160x; 1.0160x over previous
//
#include <hip/hip_runtime.h>

// Geometry (hard-coded from reference): B=8, N=1280 (256 t + 1024 s), C=768, H=12, hd=64
// Pipeline: cvt(fp32->bf16) -> gemm_qkv (scatter q*scale, k, vT bf16) -> flash attention (S^T form)
//           -> gemm_proj(+bias) -> fp32 out

typedef __attribute__((ext_vector_type(8))) short s8v;           // 8 x bf16 (MFMA A/B frag)
typedef __attribute__((ext_vector_type(4))) float f4v;           // MFMA C/D frag
typedef __attribute__((ext_vector_type(4))) unsigned short u4v;

#define MFMA16(a, b, c) __builtin_amdgcn_mfma_f32_16x16x32_bf16((a), (b), (c), 0, 0, 0)

// q pre-scale: hd^-0.5 * log2(e)  (softmax runs in exp2 domain)
#define QSCALE 0.1803368801f

__device__ __forceinline__ unsigned short f2bf(float f) {
  unsigned int u = __builtin_bit_cast(unsigned int, f);
  u += 0x7fffu + ((u >> 16) & 1u);      // round-to-nearest-even
  return (unsigned short)(u >> 16);
}

__global__ __launch_bounds__(256) void cvt_kernel(const float* __restrict__ src,
                                                  unsigned short* __restrict__ dst,
                                                  int n4) {
  int i = blockIdx.x * 256 + threadIdx.x;
  if (i < n4) {
    f4v v = ((const f4v*)src)[i];
    u4v o;
    o[0] = f2bf(v[0]); o[1] = f2bf(v[1]); o[2] = f2bf(v[2]); o[3] = f2bf(v[3]);
    ((u4v*)dst)[i] = o;
  }
}

// ---------------- 128x128 bf16 GEMM (C = A * B^T), K=768 ----------------
// QKV variant: epilogue scatters to q[b,h,n,d]*QSCALE, k[b,h,n,d], vT[b,h,d,n] (bf16).
__global__ __launch_bounds__(256) void gemm_qkv_kernel(
    const unsigned short* __restrict__ A,   // 10240 x 768 bf16 (x)
    const unsigned short* __restrict__ Bm,  // 2304 x 768 bf16 (qkv_w)
    unsigned short* __restrict__ qb, unsigned short* __restrict__ kb,
    unsigned short* __restrict__ vT) {
  const int K = 768;
  __shared__ __align__(16) unsigned short As[128 * 32];
  __shared__ __align__(16) unsigned short Bs[128 * 32];
  int tid = threadIdx.x;
  int wave = tid >> 6, lane = tid & 63;
  int quad = lane >> 4, l16 = lane & 15;
  int wm = wave >> 1, wn = wave & 1;
  int m0 = blockIdx.y * 128, n0 = blockIdx.x * 128;

  f4v acc[4][4];
#pragma unroll
  for (int i = 0; i < 4; ++i)
#pragma unroll
    for (int j = 0; j < 4; ++j) acc[i][j] = (f4v){0.f, 0.f, 0.f, 0.f};

  for (int kt = 0; kt < K; kt += 32) {
#pragma unroll
    for (int c = 0; c < 2; ++c) {
      int idx = c * 256 + tid;
      int row = idx >> 2;
      int col = (idx & 3) << 3;
      const unsigned short* ga = A + (size_t)(m0 + row) * K + (kt + col);
      const unsigned short* gb = Bm + (size_t)(n0 + row) * K + (kt + col);
      __builtin_amdgcn_global_load_lds(
          (const __attribute__((address_space(1))) unsigned int*)ga,
          (__attribute__((address_space(3))) unsigned int*)((char*)As + idx * 16), 16, 0, 0);
      __builtin_amdgcn_global_load_lds(
          (const __attribute__((address_space(1))) unsigned int*)gb,
          (__attribute__((address_space(3))) unsigned int*)((char*)Bs + idx * 16), 16, 0, 0);
    }
    __syncthreads();
    s8v af[4], bfr[4];
#pragma unroll
    for (int mi = 0; mi < 4; ++mi)
      af[mi] = *(const s8v*)&As[(wm * 64 + mi * 16 + l16) * 32 + quad * 8];
#pragma unroll
    for (int ni = 0; ni < 4; ++ni)
      bfr[ni] = *(const s8v*)&Bs[(wn * 64 + ni * 16 + l16) * 32 + quad * 8];
#pragma unroll
    for (int mi = 0; mi < 4; ++mi)
#pragma unroll
      for (int ni = 0; ni < 4; ++ni)
        acc[mi][ni] = MFMA16(af[mi], bfr[ni], acc[mi][ni]);
    __syncthreads();
  }

  // Epilogue scatter. C/D layout: row = quad*4+reg, col = l16.
#pragma unroll
  for (int ni = 0; ni < 4; ++ni) {
    int gn = n0 + wn * 64 + ni * 16 + l16;   // output channel o in [0,2304)
    int which = gn / 768;                    // 0=q 1=k 2=v (uniform per frag)
    int oo = gn - which * 768;
    int hh = oo >> 6;
    int dd = oo & 63;
#pragma unroll
    for (int mi = 0; mi < 4; ++mi) {
#pragma unroll
      for (int r = 0; r < 4; ++r) {
        int gm = m0 + wm * 64 + mi * 16 + quad * 4 + r;  // token row in [0,10240)
        int bb = gm / 1280;
        int nn = gm - bb * 1280;
        float v = acc[mi][ni][r];
        if (which == 0) {
          qb[(((size_t)bb * 12 + hh) * 1280 + nn) * 64 + dd] = f2bf(v * QSCALE);
        } else if (which == 1) {
          kb[(((size_t)bb * 12 + hh) * 1280 + nn) * 64 + dd] = f2bf(v);
        } else {
          vT[(((size_t)bb * 12 + hh) * 64 + dd) * 1280 + nn] = f2bf(v);  // V transposed
        }
      }
    }
  }
}

__global__ __launch_bounds__(256) void gemm_proj_kernel(
    const unsigned short* __restrict__ A,   // 10240 x 768 bf16 (attention out)
    const unsigned short* __restrict__ Bm,  // 768 x 768 bf16 (proj_w)
    const float* __restrict__ pb, float* __restrict__ out) {
  const int K = 768;
  __shared__ __align__(16) unsigned short As[128 * 32];
  __shared__ __align__(16) unsigned short Bs[128 * 32];
  int tid = threadIdx.x;
  int wave = tid >> 6, lane = tid & 63;
  int quad = lane >> 4, l16 = lane & 15;
  int wm = wave >> 1, wn = wave & 1;
  int m0 = blockIdx.y * 128, n0 = blockIdx.x * 128;

  f4v acc[4][4];
#pragma unroll
  for (int i = 0; i < 4; ++i)
#pragma unroll
    for (int j = 0; j < 4; ++j) acc[i][j] = (f4v){0.f, 0.f, 0.f, 0.f};

  for (int kt = 0; kt < K; kt += 32) {
#pragma unroll
    for (int c = 0; c < 2; ++c) {
      int idx = c * 256 + tid;
      int row = idx >> 2;
      int col = (idx & 3) << 3;
      const unsigned short* ga = A + (size_t)(m0 + row) * K + (kt + col);
      const unsigned short* gb = Bm + (size_t)(n0 + row) * K + (kt + col);
      __builtin_amdgcn_global_load_lds(
          (const __attribute__((address_space(1))) unsigned int*)ga,
          (__attribute__((address_space(3))) unsigned int*)((char*)As + idx * 16), 16, 0, 0);
      __builtin_amdgcn_global_load_lds(
          (const __attribute__((address_space(1))) unsigned int*)gb,
          (__attribute__((address_space(3))) unsigned int*)((char*)Bs + idx * 16), 16, 0, 0);
    }
    __syncthreads();
    s8v af[4], bfr[4];
#pragma unroll
    for (int mi = 0; mi < 4; ++mi)
      af[mi] = *(const s8v*)&As[(wm * 64 + mi * 16 + l16) * 32 + quad * 8];
#pragma unroll
    for (int ni = 0; ni < 4; ++ni)
      bfr[ni] = *(const s8v*)&Bs[(wn * 64 + ni * 16 + l16) * 32 + quad * 8];
#pragma unroll
    for (int mi = 0; mi < 4; ++mi)
#pragma unroll
      for (int ni = 0; ni < 4; ++ni)
        acc[mi][ni] = MFMA16(af[mi], bfr[ni], acc[mi][ni]);
    __syncthreads();
  }

#pragma unroll
  for (int ni = 0; ni < 4; ++ni) {
    int gn = n0 + wn * 64 + ni * 16 + l16;
    float bias = pb[gn];
#pragma unroll
    for (int mi = 0; mi < 4; ++mi)
#pragma unroll
      for (int r = 0; r < 4; ++r) {
        int gm = m0 + wm * 64 + mi * 16 + quad * 4 + r;
        out[(size_t)gm * 768 + gn] = acc[mi][ni][r] + bias;
      }
  }
}

// ---------------- Flash attention, S^T formulation ----------------
// grid (20, 12, 8); qt 0..3 -> t-branch (keys 0..255), 4..19 -> s-branch (keys 0..1279).
// block 256 = 4 waves; wave handles 16 queries x hd=64, 32-key tiles.
// S^T = K . Q^T  (A = K rows with permuted m->key map, B = Q rows loaded A-frag-style).
// S^T C-layout: lane(quad,l16) holds keys, col q = l16 -> softmax stats are per-lane scalars.
// K-row permutation: frag0 row m -> key (m>>2)*8+(m&3); frag1 -> +4. This makes the P^T
// C-frags land exactly in the 16x16x32 B-frag layout (k=quad*8+j) with ZERO cross-lane moves.
// PV: O^T = V^T . P^T, A-frag = contiguous 16B loads from vT. No LDS, no barriers.
__global__ __launch_bounds__(256) void attn_kernel(
    const unsigned short* __restrict__ qb, const unsigned short* __restrict__ kb,
    const unsigned short* __restrict__ vT, unsigned short* __restrict__ attnb) {
  const int NT = 1280, CC = 768;
  // launch long (s-branch) blocks first to shrink the tail
  int bx = blockIdx.x;
  int qt = (bx < 16) ? (bx + 4) : (bx - 16);
  int h = blockIdx.y;
  int b = blockIdx.z;
  int wave = threadIdx.x >> 6, lane = threadIdx.x & 63;
  int quad = lane >> 4, l16 = lane & 15;
  int q0 = qt * 64 + wave * 16;
  int nk = (qt < 4) ? 256 : 1280;

  const unsigned short* qp = qb + (((size_t)b * 12 + h) * NT + q0) * 64;
  const unsigned short* kp = kb + (((size_t)b * 12 + h) * NT) * 64;
  const unsigned short* vp = vT + (((size_t)b * 12 + h) * 64) * NT;

  // Q as B-frag: B[d][q] = Q[q][d] -> identical addressing to an A-frag load of Q rows
  s8v bq0 = *(const s8v*)(qp + l16 * 64 + quad * 8);
  s8v bq1 = *(const s8v*)(qp + l16 * 64 + 32 + quad * 8);

  // K A-frag row permutation (see header comment)
  int krow0 = ((l16 >> 2) << 3) + (l16 & 3);  // frag0: keys {0-3,8-11,16-19,24-27}
  int krow1 = krow0 + 4;                      // frag1: keys {4-7,12-15,20-23,28-31}

  float m_run = -1e30f, l_run = 0.f;
  f4v Oacc[4];
#pragma unroll
  for (int dt = 0; dt < 4; ++dt) Oacc[dt] = (f4v){0.f, 0.f, 0.f, 0.f};

  // prefetch K frags for k0 = 0
  s8v ka0lo = *(const s8v*)(kp + (size_t)krow0 * 64 + quad * 8);
  s8v ka0hi = *(const s8v*)(kp + (size_t)krow0 * 64 + 32 + quad * 8);
  s8v ka1lo = *(const s8v*)(kp + (size_t)krow1 * 64 + quad * 8);
  s8v ka1hi = *(const s8v*)(kp + (size_t)krow1 * 64 + 32 + quad * 8);

  for (int k0 = 0; k0 < nk; k0 += 32) {
    // QK^T (transposed): S^T frags, col = query
    f4v s0 = {0.f, 0.f, 0.f, 0.f}, s1 = {0.f, 0.f, 0.f, 0.f};
    s0 = MFMA16(ka0lo, bq0, s0);
    s0 = MFMA16(ka0hi, bq1, s0);
    s1 = MFMA16(ka1lo, bq0, s1);
    s1 = MFMA16(ka1hi, bq1, s1);

    // issue independent loads early: V for this tile, K for next tile
    s8v va[4];
#pragma unroll
    for (int dt = 0; dt < 4; ++dt)
      va[dt] = *(const s8v*)(vp + (size_t)(dt * 16 + l16) * NT + k0 + quad * 8);
    int kn = k0 + 32;
    if (kn < nk) {
      const unsigned short* kpn = kp + (size_t)kn * 64;
      ka0lo = *(const s8v*)(kpn + (size_t)krow0 * 64 + quad * 8);
      ka0hi = *(const s8v*)(kpn + (size_t)krow0 * 64 + 32 + quad * 8);
      ka1lo = *(const s8v*)(kpn + (size_t)krow1 * 64 + quad * 8);
      ka1hi = *(const s8v*)(kpn + (size_t)krow1 * 64 + 32 + quad * 8);
    }

    // online softmax in exp2 domain; per-lane scalar stats (one query per lane)
    float pm = fmaxf(fmaxf(fmaxf(s0[0], s0[1]), fmaxf(s0[2], s0[3])),
                     fmaxf(fmaxf(s1[0], s1[1]), fmaxf(s1[2], s1[3])));
    pm = fmaxf(pm, __shfl_xor(pm, 16, 64));
    pm = fmaxf(pm, __shfl_xor(pm, 32, 64));
    float nm = fmaxf(m_run, pm);
    float al = __builtin_amdgcn_exp2f(m_run - nm);
    m_run = nm;
    float p0[4], p1[4];
#pragma unroll
    for (int r = 0; r < 4; ++r) {
      p0[r] = __builtin_amdgcn_exp2f(s0[r] - nm);
      p1[r] = __builtin_amdgcn_exp2f(s1[r] - nm);
    }
    float rs = (p0[0] + p0[1]) + (p0[2] + p0[3]) + ((p1[0] + p1[1]) + (p1[2] + p1[3]));
    rs += __shfl_xor(rs, 16, 64);
    rs += __shfl_xor(rs, 32, 64);
    l_run = l_run * al + rs;
#pragma unroll
    for (int dt = 0; dt < 4; ++dt)
#pragma unroll
      for (int r = 0; r < 4; ++r) Oacc[dt][r] *= al;

    // P^T B-frag: j=0..3 from frag0 regs, j=4..7 from frag1 regs (in-lane!)
    s8v pbf;
#pragma unroll
    for (int r = 0; r < 4; ++r) {
      pbf[r] = (short)f2bf(p0[r]);
      pbf[4 + r] = (short)f2bf(p1[r]);
    }

    // O^T += V^T . P^T
#pragma unroll
    for (int dt = 0; dt < 4; ++dt) Oacc[dt] = MFMA16(va[dt], pbf, Oacc[dt]);
  }

  float inv = 1.f / l_run;
  // O^T C-layout: q = l16, d = dt*16 + quad*4 + r -> 4 consecutive bf16 = one 8B store
  size_t orow = ((size_t)b * NT + q0 + l16) * CC + h * 64;
#pragma unroll
  for (int dt = 0; dt < 4; ++dt) {
    u4v ov;
#pragma unroll
    for (int r = 0; r < 4; ++r) ov[r] = f2bf(Oacc[dt][r] * inv);
    *(u4v*)(attnb + orow + dt * 16 + quad * 4) = ov;
  }
}

extern "C" void kernel_launch(void* const* d_in, const int* in_sizes, int n_in,
                              void* d_out, int out_size, void* d_ws, size_t ws_size,
                              hipStream_t stream) {
  const float* x = (const float*)d_in[0];       // (8,1280,768)
  const float* qkv_w = (const float*)d_in[1];   // (2304,768)
  const float* proj_w = (const float*)d_in[2];  // (768,768)
  const float* proj_b = (const float*)d_in[3];  // (768,)
  float* out = (float*)d_out;

  // workspace layout (bytes)
  char* ws = (char*)d_ws;
  unsigned short* xb = (unsigned short*)(ws + 0);            // 10240*768*2 = 15,728,640
  unsigned short* wqkvb = (unsigned short*)(ws + 15728640);  // 2304*768*2  =  3,538,944
  unsigned short* wpb = (unsigned short*)(ws + 19267584);    // 768*768*2   =  1,179,648
  unsigned short* qb = (unsigned short*)(ws + 20447232);     // 15,728,640
  unsigned short* kbuf = (unsigned short*)(ws + 36175872);   // 15,728,640
  unsigned short* vT = (unsigned short*)(ws + 51904512);     // 15,728,640  -> total 67,633,152
  unsigned short* attnb = xb;  // reuse: xb dead after gemm_qkv

  cvt_kernel<<<dim3(1966080 / 256), 256, 0, stream>>>(x, xb, 1966080);
  cvt_kernel<<<dim3(442368 / 256), 256, 0, stream>>>(qkv_w, wqkvb, 442368);
  cvt_kernel<<<dim3(576), 256, 0, stream>>>(proj_w, wpb, 147456);

  gemm_qkv_kernel<<<dim3(18, 80), 256, 0, stream>>>(xb, wqkvb, qb, kbuf, vT);
  attn_kernel<<<dim3(20, 12, 8), 256, 0, stream>>>(qb, kbuf, vT, attnb);
  gemm_proj_kernel<<<dim3(6, 80), 256, 0, stream>>>(attnb, wpb, proj_b, out);
}